// Round 19
// baseline (185.363 us; speedup 1.0000x reference)
//
#include <hip/hip_runtime.h>
#include <hip/hip_fp16.h>

// Problem constants: B=4, N=2048, D=1024, H=16, DH=64.  M = B*N = 8192.

typedef _Float16 half8 __attribute__((ext_vector_type(8)));
typedef _Float16 half4 __attribute__((ext_vector_type(4)));
typedef float f32x4 __attribute__((ext_vector_type(4)));
typedef unsigned int u32x2 __attribute__((ext_vector_type(2)));

#define DEV __device__ __forceinline__
#define MFMA16(a, b, c) __builtin_amdgcn_mfma_f32_16x16x32_f16(a, b, c, 0, 0, 0)

DEV void gload_lds16(const void* g, void* l) {
  __builtin_amdgcn_global_load_lds(
      (const __attribute__((address_space(1))) void*)g,
      (__attribute__((address_space(3))) void*)l, 16, 0, 0);
}

// ---------------- fused cast f32 -> f16 (x + 4 weight matrices) ------------
__global__ __launch_bounds__(256) void cast_all(
    const float* __restrict__ x, const float* __restrict__ Wq,
    const float* __restrict__ Wk, const float* __restrict__ Wv,
    const float* __restrict__ Wp, __half* __restrict__ xb,
    __half* __restrict__ wqkv, __half* __restrict__ wpb) {
  int i = blockIdx.x * 256 + threadIdx.x;
  const float* s;
  __half* d;
  int j;
  if (i < 1048576) {
    s = x; d = xb; j = i;
  } else {
    int k = i - 1048576;
    int sel = k >> 17;
    j = k & 131071;
    s = (sel == 0) ? Wq : (sel == 1) ? Wk : (sel == 2) ? Wv : Wp;
    d = (sel == 3) ? wpb : (wqkv + sel * 1048576);
  }
  const float4* sp = (const float4*)s + (size_t)j * 2;
  float4 a = sp[0], b = sp[1];
  half8 h;
  h[0] = (_Float16)a.x; h[1] = (_Float16)a.y; h[2] = (_Float16)a.z; h[3] = (_Float16)a.w;
  h[4] = (_Float16)b.x; h[5] = (_Float16)b.y; h[6] = (_Float16)b.z; h[7] = (_Float16)b.w;
  *((half8*)d + j) = h;
}

// ---------------- 256x192 QKV GEMM, 4-phase/K-tile counted-vmcnt schedule --
// (r17, verified: 73.4us, zero bank conflicts)
__global__ __launch_bounds__(512, 2) void gemmQKV(
    const __half* __restrict__ A, const __half* __restrict__ Bm,
    const float* __restrict__ b0, const float* __restrict__ b1,
    const float* __restrict__ b2, __half* __restrict__ oh,
    __half* __restrict__ vtp) {
  const int m0 = blockIdx.y * 256;
  const int n0 = blockIdx.x * 192;
  const int tid = threadIdx.x;
  const int w = tid >> 6, lane = tid & 63;
  const int lr = lane & 15, lq = lane >> 4;
  const int wr = w >> 2, wc = w & 3;

  __shared__ alignas(16) __half As[2][16384];  // 256 x 64, swizzled
  __shared__ alignas(16) __half Bs[2][12288];  // 192 x 64, swizzled

  f32x4 acc[2][4][3] = {};

  const int srow = tid >> 3;
  const int scol = ((tid & 7) ^ (srow & 7)) * 8;
  const __half* Agp = A + ((size_t)m0 + srow) * 1024 + scol;
  const __half* Bgp = Bm + ((size_t)n0 + srow) * 1024 + scol;

#define SPAIR(T, BUF, P)                                                       \
  do {                                                                         \
    if ((P) == 0) {                                                            \
      gload_lds16(Agp + (T)*64, As[BUF] + tid * 8);                            \
      gload_lds16(Agp + (T)*64 + 65536, As[BUF] + 4096 + tid * 8);             \
    } else if ((P) == 1) {                                                     \
      gload_lds16(Agp + (T)*64 + 131072, As[BUF] + 8192 + tid * 8);            \
      gload_lds16(Agp + (T)*64 + 196608, As[BUF] + 12288 + tid * 8);           \
    } else if ((P) == 2) {                                                     \
      gload_lds16(Bgp + (T)*64, Bs[BUF] + tid * 8);                            \
      gload_lds16(Bgp + (T)*64 + 65536, Bs[BUF] + 4096 + tid * 8);             \
    } else {                                                                   \
      gload_lds16(Bgp + (T)*64 + 131072, Bs[BUF] + 8192 + tid * 8);            \
    }                                                                          \
  } while (0)

#define RD_A(af, Ac, mh, ks)                                                   \
  do {                                                                         \
    _Pragma("unroll") for (int mi = 0; mi < 4; ++mi) {                         \
      int row = wr * 128 + (mh)*64 + mi * 16 + lr;                             \
      af[mi] = *(const half8*)((Ac) +                                          \
                               ((row * 128 + (ks)*64 + lq * 16) ^ ((row & 7) << 4))); \
    }                                                                          \
  } while (0)

#define RD_B(bf, Bc, ks)                                                       \
  do {                                                                         \
    _Pragma("unroll") for (int ni = 0; ni < 3; ++ni) {                         \
      int row = wc * 48 + ni * 16 + lr;                                        \
      bf[ni] = *(const half8*)((Bc) +                                          \
                               ((row * 128 + (ks)*64 + lq * 16) ^ ((row & 7) << 4))); \
    }                                                                          \
  } while (0)

#define CLUSTER(mh, af, bf)                                                    \
  do {                                                                         \
    __builtin_amdgcn_s_setprio(1);                                             \
    _Pragma("unroll") for (int mi = 0; mi < 4; ++mi) {                         \
      acc[mh][mi][0] = MFMA16(af[mi], bf[0], acc[mh][mi][0]);                  \
      acc[mh][mi][1] = MFMA16(af[mi], bf[1], acc[mh][mi][1]);                  \
      acc[mh][mi][2] = MFMA16(af[mi], bf[2], acc[mh][mi][2]);                  \
    }                                                                          \
    __builtin_amdgcn_s_setprio(0);                                             \
  } while (0)

#define BAR()                                                                  \
  do {                                                                         \
    asm volatile("" ::: "memory");                                             \
    __builtin_amdgcn_s_barrier();                                              \
    asm volatile("" ::: "memory");                                             \
  } while (0)

  SPAIR(0, 0, 0);
  SPAIR(0, 0, 1);
  SPAIR(0, 0, 2);
  SPAIR(0, 0, 3);
  asm volatile("" ::: "memory");

  for (int t = 0; t < 16; ++t) {
    const int s = t & 1;
    const char* Ac = (const char*)As[s];
    const char* Bc = (const char*)Bs[s];
    half8 af[4], bf0[3], bf1[3];

    // ---- phase 0 (ks0, mh0) ----
    if (t < 15) {
      SPAIR(t + 1, s ^ 1, 0);
      asm volatile("s_waitcnt vmcnt(2)" ::: "memory");
    } else {
      asm volatile("s_waitcnt vmcnt(0)" ::: "memory");
    }
    BAR();
    RD_B(bf0, Bc, 0);
    RD_A(af, Ac, 0, 0);
    CLUSTER(0, af, bf0);
    BAR();
    // ---- phase 1 (ks0, mh1) ----
    RD_A(af, Ac, 1, 0);
    if (t < 15) SPAIR(t + 1, s ^ 1, 1);
    CLUSTER(1, af, bf0);
    BAR();
    // ---- phase 2 (ks1, mh0) ----
    RD_B(bf1, Bc, 1);
    RD_A(af, Ac, 0, 1);
    if (t < 15) SPAIR(t + 1, s ^ 1, 2);
    CLUSTER(0, af, bf1);
    BAR();
    // ---- phase 3 (ks1, mh1) ----
    RD_A(af, Ac, 1, 1);
    if (t < 15) SPAIR(t + 1, s ^ 1, 3);
    CLUSTER(1, af, bf1);
    BAR();
  }

  // ---- QKV scatter epilogue ----
#pragma unroll
  for (int mh = 0; mh < 2; ++mh)
#pragma unroll
    for (int ni = 0; ni < 3; ++ni) {
      int col = n0 + wc * 48 + ni * 16 + lr;
      int t = col >> 10, e = col & 1023;
      const float* bb = (t == 0) ? b0 : ((t == 1) ? b1 : b2);
      float bias = bb[e];
      int hh = e >> 6, dh = e & 63;
      if (t == 2) {
#pragma unroll
        for (int mi = 0; mi < 4; ++mi) {
          int row = m0 + wr * 128 + mh * 64 + mi * 16 + lq * 4;
          int b_ = row >> 11, n = row & 2047;
          half4 h;
#pragma unroll
          for (int r = 0; r < 4; ++r) h[r] = (_Float16)(acc[mh][mi][ni][r] + bias);
          *(half4*)(vtp + (size_t)(b_ * 16 + hh) * 131072 + (size_t)dh * 2048 + n) = h;
        }
      } else {
        float scale = (t == 0) ? 11.541560327111707f : 1.0f;
        __half* base = oh + (size_t)t * 8388608 + dh;
#pragma unroll
        for (int mi = 0; mi < 4; ++mi)
#pragma unroll
          for (int r = 0; r < 4; ++r) {
            int row = m0 + wr * 128 + mh * 64 + mi * 16 + lq * 4 + r;
            int b_ = row >> 11, n = row & 2047;
            float v = (acc[mh][mi][ni][r] + bias) * scale;
            base[(((size_t)(b_ * 16 + hh) * 2048 + n) * 64)] = __float2half(v);
          }
      }
    }
#undef SPAIR
#undef RD_A
#undef RD_B
#undef CLUSTER
#undef BAR
}

// ---------------- 128x128 GEMM (proj), T2-swizzled LDS ---------------------
__global__ __launch_bounds__(256) void gemm128p(
    const __half* __restrict__ A, const __half* __restrict__ Bm,
    const float* __restrict__ b0, float* __restrict__ of) {
  const int m0 = blockIdx.y * 128;
  const int n0 = blockIdx.x * 128;
  const int tid = threadIdx.x;
  const int w = tid >> 6, lane = tid & 63;
  const int lr = lane & 15, lq = lane >> 4;
  const int wr = w >> 1, wc = w & 1;

  __shared__ alignas(16) __half As[128 * 64];
  __shared__ alignas(16) __half Bs[128 * 64];

  f32x4 acc[4][4] = {};

  const int arow = lane >> 3;
  const int acol = ((lane & 7) ^ arow) * 8;
  const __half* Agp = A + ((size_t)m0 + w * 32 + arow) * 1024 + acol;
  const __half* Bgp = Bm + ((size_t)n0 + w * 32 + arow) * 1024 + acol;

  for (int kt = 0; kt < 16; ++kt) {
#pragma unroll
    for (int j = 0; j < 4; ++j) {
      gload_lds16(Agp + j * 8192 + kt * 64, As + (w * 4 + j) * 512);
      gload_lds16(Bgp + j * 8192 + kt * 64, Bs + (w * 4 + j) * 512);
    }
    __syncthreads();
#pragma unroll
    for (int s = 0; s < 2; ++s) {
      half8 af[4], bf[4];
#pragma unroll
      for (int i = 0; i < 4; ++i) {
        int rowA = wr * 64 + i * 16 + lr;
        int rowB = wc * 64 + i * 16 + lr;
        af[i] = *(const half8*)((const char*)As +
                                ((rowA * 128 + s * 64 + lq * 16) ^ ((rowA & 7) << 4)));
        bf[i] = *(const half8*)((const char*)Bs +
                                ((rowB * 128 + s * 64 + lq * 16) ^ ((rowB & 7) << 4)));
      }
#pragma unroll
      for (int mi = 0; mi < 4; ++mi)
#pragma unroll
        for (int ni = 0; ni < 4; ++ni)
          acc[mi][ni] = MFMA16(af[mi], bf[ni], acc[mi][ni]);
    }
    __syncthreads();
  }

#pragma unroll
  for (int ni = 0; ni < 4; ++ni) {
    int col = n0 + wc * 64 + ni * 16 + lr;
    float bias = b0[col];
#pragma unroll
    for (int mi = 0; mi < 4; ++mi)
#pragma unroll
      for (int r = 0; r < 4; ++r) {
        int row = m0 + wr * 64 + mi * 16 + lq * 4 + r;
        of[(size_t)row * 1024 + col] = acc[mi][ni][r] + bias;
      }
  }
}

// ---------------- causal flash attention, dual-Q + 3-slot ring -------------
// Q,K: [bh][2048][64] f16 (Q pre-scaled by 8*log2e).  Vt: [bh][64][2048] f16.
// O: [b][n][h*64+dh] f16.
// Grid 1024 (r17's proven shape): bh = wg&63 XCD-affine, qt = 15-(wg>>6)
// longest-first.  Body = r15's verified dual-Q swapped-operand kernel.
// NEW: 3-slot LDS ring with ONE barrier per kv-tile (the 2-slot ring needed
// an exit barrier + lgkmcnt(0) drain).  Safety: STAGE(kt+2 -> slot (kt+2)%3
// == slot (kt-1)%3) is issued AFTER the entry barrier of iter kt, at which
// point every wave is >= iter kt and all reads of slot (kt-1)%3 were already
// consumed by MFMAs (compiler lgkmcnt precedes use).  vmcnt in-order: at
// entry outstanding <= 8 (tiles kt,kt+1); vmcnt(4) certifies tile kt.
// LDS 50 KB -> 3 blocks/CU (was 4): trade 25% wave cap for 50% fewer
// barrier rendezvous on the serial chain.
__global__ __launch_bounds__(256, 3) void attn128(const __half* __restrict__ Q,
                                                  const __half* __restrict__ K,
                                                  const __half* __restrict__ Vt,
                                                  __half* __restrict__ O) {
  const int wg = blockIdx.x;
  const int bh = wg & 63;
  const int qt = 15 - (wg >> 6);
  const int b = bh >> 4, h = bh & 15;
  const int tid = threadIdx.x;
  const int w = tid >> 6, lane = tid & 63;
  const int lr = lane & 15, lq = lane >> 4;

  __shared__ alignas(16) __half Ks[3][4096];
  __shared__ alignas(16) __half Vs[3][4096];
  __shared__ alignas(16) unsigned Pl[4][512];  // per-wave P: [16 q][32 u32]

  const __half* Kb = K + (size_t)bh * 131072;
  const __half* Vb = Vt + (size_t)bh * 131072;

  const int srow0 = tid >> 3;
  const int srow1 = srow0 + 32;
  const int scol = ((tid & 7) ^ (srow0 & 7)) * 8;

#define STAGE(t, buf)                                                          \
  do {                                                                         \
    gload_lds16(Kb + (size_t)((t)*64 + srow0) * 64 + scol, Ks[buf] + tid * 8); \
    gload_lds16(Kb + (size_t)((t)*64 + srow1) * 64 + scol,                     \
                Ks[buf] + 2048 + tid * 8);                                     \
    gload_lds16(Vb + (size_t)srow0 * 2048 + (t)*64 + scol, Vs[buf] + tid * 8); \
    gload_lds16(Vb + (size_t)srow1 * 2048 + (t)*64 + scol,                     \
                Vs[buf] + 2048 + tid * 8);                                     \
  } while (0)

  const int q0 = qt * 128;
  const int ktend = 2 * qt + 2;
  const int rmin = q0 + w * 32;
  const int myqa = rmin + lr;
  const int myqb = rmin + 16 + lr;

  const __half* Qpa = Q + ((size_t)bh * 2048 + rmin) * 64;
  half8 qf0a = *(const half8*)(Qpa + lr * 64 + lq * 8);
  half8 qf1a = *(const half8*)(Qpa + lr * 64 + 32 + lq * 8);
  half8 qf0b = *(const half8*)(Qpa + (16 + lr) * 64 + lq * 8);
  half8 qf1b = *(const half8*)(Qpa + (16 + lr) * 64 + 32 + lq * 8);

  f32x4 oacca[4] = {}, oaccb[4] = {};
  float ma = -INFINITY, la = 0.f, mb = -INFINITY, lb = 0.f;

  // prologue: tiles 0 and 1 in flight (tile 1 exists: ktend >= 2 always)
  STAGE(0, 0);
  STAGE(1, 1);
  asm volatile("" ::: "memory");

  char* Pc = (char*)Pl[w];

  // softmax + pack + LDS round-trip for one 16-q group (inlined twice).
  auto smgrp = [&](f32x4* sacc, float& m, float& l, int myq, int k0,
                   bool needmask, f32x4* oacc, half8& pa0, half8& pa1) {
    if (needmask) {
#pragma unroll
      for (int nt = 0; nt < 4; ++nt)
#pragma unroll
        for (int r = 0; r < 4; ++r) {
          int key = k0 + nt * 16 + lq * 4 + r;
          if (key > myq) sacc[nt][r] = -INFINITY;
        }
    }
    float rm = fmaxf(sacc[0][0], sacc[0][1]);
    rm = fmaxf(fmaxf(rm, sacc[0][2]), sacc[0][3]);
    rm = fmaxf(fmaxf(rm, sacc[1][0]), sacc[1][1]);
    rm = fmaxf(fmaxf(rm, sacc[1][2]), sacc[1][3]);
    rm = fmaxf(fmaxf(rm, sacc[2][0]), sacc[2][1]);
    rm = fmaxf(fmaxf(rm, sacc[2][2]), sacc[2][3]);
    rm = fmaxf(fmaxf(rm, sacc[3][0]), sacc[3][1]);
    rm = fmaxf(fmaxf(rm, sacc[3][2]), sacc[3][3]);
    rm = fmaxf(rm, __shfl_xor(rm, 16));
    rm = fmaxf(rm, __shfl_xor(rm, 32));
    if (__any(rm > m + 8.f)) {  // defer-max (T13)
      float mn = fmaxf(m, rm);
      float al = __builtin_amdgcn_exp2f(m - mn);
      m = mn;
      l *= al;
      float al4[4];
#pragma unroll
      for (int r = 0; r < 4; ++r) al4[r] = __shfl(al, lq * 4 + r);
#pragma unroll
      for (int dt = 0; dt < 4; ++dt)
#pragma unroll
        for (int r = 0; r < 4; ++r) oacc[dt][r] *= al4[r];
    }
    float ps = 0.f;
#pragma unroll
    for (int nt = 0; nt < 4; ++nt) {
      float p0 = __builtin_amdgcn_exp2f(sacc[nt][0] - m);
      float p1 = __builtin_amdgcn_exp2f(sacc[nt][1] - m);
      float p2 = __builtin_amdgcn_exp2f(sacc[nt][2] - m);
      float p3 = __builtin_amdgcn_exp2f(sacc[nt][3] - m);
      sacc[nt][0] = p0; sacc[nt][1] = p1;
      sacc[nt][2] = p2; sacc[nt][3] = p3;
      ps += (p0 + p1) + (p2 + p3);
    }
    l += ps;  // deferred: cross-lane reduce once in epilogue
#pragma unroll
    for (int nt = 0; nt < 4; ++nt) {
      __half2 pha = __floats2half2_rn(sacc[nt][0], sacc[nt][1]);
      __half2 phb = __floats2half2_rn(sacc[nt][2], sacc[nt][3]);
      u32x2 pw;
      pw[0] = *(unsigned*)&pha;
      pw[1] = *(unsigned*)&phb;
      *(u32x2*)(Pc + ((lr * 128 + nt * 32 + lq * 8) ^ ((lr & 7) << 4))) = pw;
    }
    pa0 = *(const half8*)(Pc + ((lr * 128 + lq * 16) ^ ((lr & 7) << 4)));
    pa1 = *(const half8*)(Pc + ((lr * 128 + 64 + lq * 16) ^ ((lr & 7) << 4)));
  };

  for (int kt = 0; kt < ktend; ++kt) {
    const int cur = kt % 3;
    const int k0 = kt * 64;
    // entry wait: certify tile kt (vmcnt(4) leaves tile kt+1's 4 in flight)
    if (kt + 1 < ktend) asm volatile("s_waitcnt vmcnt(4)" ::: "memory");
    else                asm volatile("s_waitcnt vmcnt(0)" ::: "memory");
    __builtin_amdgcn_s_barrier();
    asm volatile("" ::: "memory");
    // stage tile kt+2 into slot (kt+2)%3 (== slot (kt-1)%3, fully consumed)
    if (kt + 2 < ktend) STAGE(kt + 2, (kt + 2) % 3);

    const char* Kc = (const char*)Ks[cur];
    const char* Vc = (const char*)Vs[cur];
    if (k0 <= rmin + 31) {
      f32x4 sa[4] = {}, sb[4] = {};
      __builtin_amdgcn_s_setprio(1);
#pragma unroll
      for (int nt = 0; nt < 4; ++nt) {
        int row = nt * 16 + lr;
        half8 kb0 = *(const half8*)(Kc + ((row * 128 + lq * 16) ^ ((row & 7) << 4)));
        half8 kb1 = *(const half8*)(Kc + ((row * 128 + 64 + lq * 16) ^ ((row & 7) << 4)));
        sa[nt] = MFMA16(kb0, qf0a, sa[nt]);
        sa[nt] = MFMA16(kb1, qf1a, sa[nt]);
        sb[nt] = MFMA16(kb0, qf0b, sb[nt]);
        sb[nt] = MFMA16(kb1, qf1b, sb[nt]);
      }
      __builtin_amdgcn_s_setprio(0);

      half8 paa0, paa1, pab0, pab1;
      smgrp(sa, ma, la, myqa, k0, k0 + 63 > rmin, oacca, paa0, paa1);
      smgrp(sb, mb, lb, myqb, k0, k0 + 63 > rmin + 16, oaccb, pab0, pab1);

      __builtin_amdgcn_s_setprio(1);
#pragma unroll
      for (int dt = 0; dt < 4; ++dt) {
        int row = dt * 16 + lr;
        half8 vb0 = *(const half8*)(Vc + ((row * 128 + lq * 16) ^ ((row & 7) << 4)));
        half8 vb1 = *(const half8*)(Vc + ((row * 128 + 64 + lq * 16) ^ ((row & 7) << 4)));
        oacca[dt] = MFMA16(paa0, vb0, oacca[dt]);
        oacca[dt] = MFMA16(paa1, vb1, oacca[dt]);
        oaccb[dt] = MFMA16(pab0, vb0, oaccb[dt]);
        oaccb[dt] = MFMA16(pab1, vb1, oaccb[dt]);
      }
      __builtin_amdgcn_s_setprio(0);
    }
    // no exit barrier: 3-slot ring tolerates 1-iter wave skew
  }

  // epilogue: reduce deferred l across the 4 lane-groups, broadcast, write
  auto epi = [&](f32x4* oacc, float lpart, int grow) {
    float lt = lpart;
    lt += __shfl_xor(lt, 16);
    lt += __shfl_xor(lt, 32);
    float linv = 1.0f / lt;
    float inv4[4];
#pragma unroll
    for (int r = 0; r < 4; ++r) inv4[r] = __shfl(linv, lq * 4 + r);
    __half* Op = O + ((size_t)b * 2048 + rmin + grow) * 1024 + h * 64;
#pragma unroll
    for (int dt = 0; dt < 4; ++dt)
#pragma unroll
      for (int r = 0; r < 4; ++r)
        Op[(size_t)(lq * 4 + r) * 1024 + dt * 16 + lr] =
            __float2half(oacc[dt][r] * inv4[r]);
  };
  epi(oacca, la, 0);
  epi(oaccb, lb, 16);
#undef STAGE
}

// ---------------- launch ---------------------------------------------------
extern "C" void kernel_launch(void* const* d_in, const int* in_sizes, int n_in,
                              void* d_out, int out_size, void* d_ws,
                              size_t ws_size, hipStream_t stream) {
  const float* x = (const float*)d_in[0];
  const float* Wq = (const float*)d_in[1];
  const float* bq = (const float*)d_in[2];
  const float* Wk = (const float*)d_in[3];
  const float* bk = (const float*)d_in[4];
  const float* Wv = (const float*)d_in[5];
  const float* bv = (const float*)d_in[6];
  const float* Wp = (const float*)d_in[7];
  const float* bp = (const float*)d_in[8];

  // workspace layout (bytes)
  char* ws = (char*)d_ws;
  const size_t XB = 0;                       // 16777216
  const size_t WQKV = XB + 16777216;         // 6291456
  const size_t WPB = WQKV + 6291456;         // 2097152
  const size_t QKV = WPB + 2097152;          // 50331648 (v slot unused)
  const size_t VT = QKV + 50331648;          // 16777216
  const size_t OB = VT + 16777216;           // 16777216  (~109 MiB)

  __half* xb = (__half*)(ws + XB);
  __half* wqkv = (__half*)(ws + WQKV);
  __half* wpb = (__half*)(ws + WPB);
  __half* qkv = (__half*)(ws + QKV);
  __half* vt = (__half*)(ws + VT);
  __half* ob = (__half*)(ws + OB);

  // fused cast: x + Wq + Wk + Wv + Wp (1572864 half8 units)
  cast_all<<<6144, 256, 0, stream>>>(x, Wq, Wk, Wv, Wp, xb, wqkv, wpb);

  // QKV: M=8192, N=3072, 256x192 tile, 4-phase counted-vmcnt schedule
  gemmQKV<<<dim3(16, 32), 512, 0, stream>>>(xb, wqkv, bq, bk, bv, qkv, vt);
  // attention: 1024 blocks, longest-first, 3-slot ring single-barrier
  attn128<<<dim3(1024), 256, 0, stream>>>(qkv, qkv + 8388608, vt, ob);
  // proj: M=8192, N=1024, f32 out + bias (T2-swizzled LDS)
  gemm128p<<<dim3(8, 64), 256, 0, stream>>>(ob, wpb, bp, (float*)d_out);
}

// Round 20
// 167.948 us; speedup vs baseline: 1.1037x; 1.1037x over previous
//
#include <hip/hip_runtime.h>
#include <hip/hip_fp16.h>

// Problem constants: B=4, N=2048, D=1024, H=16, DH=64.  M = B*N = 8192.
// Round 20 = exact revert to the round-17 best (167.6 us): r15 attn +
// r17 4-phase gemmQKV + T2 proj + fused cast.  r18 (pairing) and r19
// (3-slot ring) both regressed by dropping resident blocks/CU.

typedef _Float16 half8 __attribute__((ext_vector_type(8)));
typedef _Float16 half4 __attribute__((ext_vector_type(4)));
typedef float f32x4 __attribute__((ext_vector_type(4)));
typedef unsigned int u32x2 __attribute__((ext_vector_type(2)));

#define DEV __device__ __forceinline__
#define MFMA16(a, b, c) __builtin_amdgcn_mfma_f32_16x16x32_f16(a, b, c, 0, 0, 0)

DEV void gload_lds16(const void* g, void* l) {
  __builtin_amdgcn_global_load_lds(
      (const __attribute__((address_space(1))) void*)g,
      (__attribute__((address_space(3))) void*)l, 16, 0, 0);
}

// ---------------- fused cast f32 -> f16 (x + 4 weight matrices) ------------
__global__ __launch_bounds__(256) void cast_all(
    const float* __restrict__ x, const float* __restrict__ Wq,
    const float* __restrict__ Wk, const float* __restrict__ Wv,
    const float* __restrict__ Wp, __half* __restrict__ xb,
    __half* __restrict__ wqkv, __half* __restrict__ wpb) {
  int i = blockIdx.x * 256 + threadIdx.x;
  const float* s;
  __half* d;
  int j;
  if (i < 1048576) {
    s = x; d = xb; j = i;
  } else {
    int k = i - 1048576;
    int sel = k >> 17;
    j = k & 131071;
    s = (sel == 0) ? Wq : (sel == 1) ? Wk : (sel == 2) ? Wv : Wp;
    d = (sel == 3) ? wpb : (wqkv + sel * 1048576);
  }
  const float4* sp = (const float4*)s + (size_t)j * 2;
  float4 a = sp[0], b = sp[1];
  half8 h;
  h[0] = (_Float16)a.x; h[1] = (_Float16)a.y; h[2] = (_Float16)a.z; h[3] = (_Float16)a.w;
  h[4] = (_Float16)b.x; h[5] = (_Float16)b.y; h[6] = (_Float16)b.z; h[7] = (_Float16)b.w;
  *((half8*)d + j) = h;
}

// ---------------- 256x192 QKV GEMM, 4-phase/K-tile counted-vmcnt schedule --
// (r17, verified: 73.4us, zero bank conflicts)
__global__ __launch_bounds__(512, 2) void gemmQKV(
    const __half* __restrict__ A, const __half* __restrict__ Bm,
    const float* __restrict__ b0, const float* __restrict__ b1,
    const float* __restrict__ b2, __half* __restrict__ oh,
    __half* __restrict__ vtp) {
  const int m0 = blockIdx.y * 256;
  const int n0 = blockIdx.x * 192;
  const int tid = threadIdx.x;
  const int w = tid >> 6, lane = tid & 63;
  const int lr = lane & 15, lq = lane >> 4;
  const int wr = w >> 2, wc = w & 3;

  __shared__ alignas(16) __half As[2][16384];  // 256 x 64, swizzled
  __shared__ alignas(16) __half Bs[2][12288];  // 192 x 64, swizzled

  f32x4 acc[2][4][3] = {};

  const int srow = tid >> 3;
  const int scol = ((tid & 7) ^ (srow & 7)) * 8;
  const __half* Agp = A + ((size_t)m0 + srow) * 1024 + scol;
  const __half* Bgp = Bm + ((size_t)n0 + srow) * 1024 + scol;

#define SPAIR(T, BUF, P)                                                       \
  do {                                                                         \
    if ((P) == 0) {                                                            \
      gload_lds16(Agp + (T)*64, As[BUF] + tid * 8);                            \
      gload_lds16(Agp + (T)*64 + 65536, As[BUF] + 4096 + tid * 8);             \
    } else if ((P) == 1) {                                                     \
      gload_lds16(Agp + (T)*64 + 131072, As[BUF] + 8192 + tid * 8);            \
      gload_lds16(Agp + (T)*64 + 196608, As[BUF] + 12288 + tid * 8);           \
    } else if ((P) == 2) {                                                     \
      gload_lds16(Bgp + (T)*64, Bs[BUF] + tid * 8);                            \
      gload_lds16(Bgp + (T)*64 + 65536, Bs[BUF] + 4096 + tid * 8);             \
    } else {                                                                   \
      gload_lds16(Bgp + (T)*64 + 131072, Bs[BUF] + 8192 + tid * 8);            \
    }                                                                          \
  } while (0)

#define RD_A(af, Ac, mh, ks)                                                   \
  do {                                                                         \
    _Pragma("unroll") for (int mi = 0; mi < 4; ++mi) {                         \
      int row = wr * 128 + (mh)*64 + mi * 16 + lr;                             \
      af[mi] = *(const half8*)((Ac) +                                          \
                               ((row * 128 + (ks)*64 + lq * 16) ^ ((row & 7) << 4))); \
    }                                                                          \
  } while (0)

#define RD_B(bf, Bc, ks)                                                       \
  do {                                                                         \
    _Pragma("unroll") for (int ni = 0; ni < 3; ++ni) {                         \
      int row = wc * 48 + ni * 16 + lr;                                        \
      bf[ni] = *(const half8*)((Bc) +                                          \
                               ((row * 128 + (ks)*64 + lq * 16) ^ ((row & 7) << 4))); \
    }                                                                          \
  } while (0)

#define CLUSTER(mh, af, bf)                                                    \
  do {                                                                         \
    __builtin_amdgcn_s_setprio(1);                                             \
    _Pragma("unroll") for (int mi = 0; mi < 4; ++mi) {                         \
      acc[mh][mi][0] = MFMA16(af[mi], bf[0], acc[mh][mi][0]);                  \
      acc[mh][mi][1] = MFMA16(af[mi], bf[1], acc[mh][mi][1]);                  \
      acc[mh][mi][2] = MFMA16(af[mi], bf[2], acc[mh][mi][2]);                  \
    }                                                                          \
    __builtin_amdgcn_s_setprio(0);                                             \
  } while (0)

#define BAR()                                                                  \
  do {                                                                         \
    asm volatile("" ::: "memory");                                             \
    __builtin_amdgcn_s_barrier();                                              \
    asm volatile("" ::: "memory");                                             \
  } while (0)

  SPAIR(0, 0, 0);
  SPAIR(0, 0, 1);
  SPAIR(0, 0, 2);
  SPAIR(0, 0, 3);
  asm volatile("" ::: "memory");

  for (int t = 0; t < 16; ++t) {
    const int s = t & 1;
    const char* Ac = (const char*)As[s];
    const char* Bc = (const char*)Bs[s];
    half8 af[4], bf0[3], bf1[3];

    // ---- phase 0 (ks0, mh0) ----
    if (t < 15) {
      SPAIR(t + 1, s ^ 1, 0);
      asm volatile("s_waitcnt vmcnt(2)" ::: "memory");
    } else {
      asm volatile("s_waitcnt vmcnt(0)" ::: "memory");
    }
    BAR();
    RD_B(bf0, Bc, 0);
    RD_A(af, Ac, 0, 0);
    CLUSTER(0, af, bf0);
    BAR();
    // ---- phase 1 (ks0, mh1) ----
    RD_A(af, Ac, 1, 0);
    if (t < 15) SPAIR(t + 1, s ^ 1, 1);
    CLUSTER(1, af, bf0);
    BAR();
    // ---- phase 2 (ks1, mh0) ----
    RD_B(bf1, Bc, 1);
    RD_A(af, Ac, 0, 1);
    if (t < 15) SPAIR(t + 1, s ^ 1, 2);
    CLUSTER(0, af, bf1);
    BAR();
    // ---- phase 3 (ks1, mh1) ----
    RD_A(af, Ac, 1, 1);
    if (t < 15) SPAIR(t + 1, s ^ 1, 3);
    CLUSTER(1, af, bf1);
    BAR();
  }

  // ---- QKV scatter epilogue ----
#pragma unroll
  for (int mh = 0; mh < 2; ++mh)
#pragma unroll
    for (int ni = 0; ni < 3; ++ni) {
      int col = n0 + wc * 48 + ni * 16 + lr;
      int t = col >> 10, e = col & 1023;
      const float* bb = (t == 0) ? b0 : ((t == 1) ? b1 : b2);
      float bias = bb[e];
      int hh = e >> 6, dh = e & 63;
      if (t == 2) {
#pragma unroll
        for (int mi = 0; mi < 4; ++mi) {
          int row = m0 + wr * 128 + mh * 64 + mi * 16 + lq * 4;
          int b_ = row >> 11, n = row & 2047;
          half4 h;
#pragma unroll
          for (int r = 0; r < 4; ++r) h[r] = (_Float16)(acc[mh][mi][ni][r] + bias);
          *(half4*)(vtp + (size_t)(b_ * 16 + hh) * 131072 + (size_t)dh * 2048 + n) = h;
        }
      } else {
        float scale = (t == 0) ? 11.541560327111707f : 1.0f;
        __half* base = oh + (size_t)t * 8388608 + dh;
#pragma unroll
        for (int mi = 0; mi < 4; ++mi)
#pragma unroll
          for (int r = 0; r < 4; ++r) {
            int row = m0 + wr * 128 + mh * 64 + mi * 16 + lq * 4 + r;
            int b_ = row >> 11, n = row & 2047;
            float v = (acc[mh][mi][ni][r] + bias) * scale;
            base[(((size_t)(b_ * 16 + hh) * 2048 + n) * 64)] = __float2half(v);
          }
      }
    }
#undef SPAIR
#undef RD_A
#undef RD_B
#undef CLUSTER
#undef BAR
}

// ---------------- 128x128 GEMM (proj), T2-swizzled LDS ---------------------
__global__ __launch_bounds__(256) void gemm128p(
    const __half* __restrict__ A, const __half* __restrict__ Bm,
    const float* __restrict__ b0, float* __restrict__ of) {
  const int m0 = blockIdx.y * 128;
  const int n0 = blockIdx.x * 128;
  const int tid = threadIdx.x;
  const int w = tid >> 6, lane = tid & 63;
  const int lr = lane & 15, lq = lane >> 4;
  const int wr = w >> 1, wc = w & 1;

  __shared__ alignas(16) __half As[128 * 64];
  __shared__ alignas(16) __half Bs[128 * 64];

  f32x4 acc[4][4] = {};

  const int arow = lane >> 3;
  const int acol = ((lane & 7) ^ arow) * 8;
  const __half* Agp = A + ((size_t)m0 + w * 32 + arow) * 1024 + acol;
  const __half* Bgp = Bm + ((size_t)n0 + w * 32 + arow) * 1024 + acol;

  for (int kt = 0; kt < 16; ++kt) {
#pragma unroll
    for (int j = 0; j < 4; ++j) {
      gload_lds16(Agp + j * 8192 + kt * 64, As + (w * 4 + j) * 512);
      gload_lds16(Bgp + j * 8192 + kt * 64, Bs + (w * 4 + j) * 512);
    }
    __syncthreads();
#pragma unroll
    for (int s = 0; s < 2; ++s) {
      half8 af[4], bf[4];
#pragma unroll
      for (int i = 0; i < 4; ++i) {
        int rowA = wr * 64 + i * 16 + lr;
        int rowB = wc * 64 + i * 16 + lr;
        af[i] = *(const half8*)((const char*)As +
                                ((rowA * 128 + s * 64 + lq * 16) ^ ((rowA & 7) << 4)));
        bf[i] = *(const half8*)((const char*)Bs +
                                ((rowB * 128 + s * 64 + lq * 16) ^ ((rowB & 7) << 4)));
      }
#pragma unroll
      for (int mi = 0; mi < 4; ++mi)
#pragma unroll
        for (int ni = 0; ni < 4; ++ni)
          acc[mi][ni] = MFMA16(af[mi], bf[ni], acc[mi][ni]);
    }
    __syncthreads();
  }

#pragma unroll
  for (int ni = 0; ni < 4; ++ni) {
    int col = n0 + wc * 64 + ni * 16 + lr;
    float bias = b0[col];
#pragma unroll
    for (int mi = 0; mi < 4; ++mi)
#pragma unroll
      for (int r = 0; r < 4; ++r) {
        int row = m0 + wr * 64 + mi * 16 + lq * 4 + r;
        of[(size_t)row * 1024 + col] = acc[mi][ni][r] + bias;
      }
  }
}

// ---------------- causal flash attention (r15, verified: ~62us) ------------
// Q,K: [bh][2048][64] f16 (Q pre-scaled by 8*log2e).  Vt: [bh][64][2048] f16.
// O: [b][n][h*64+dh] f16.
// 256 thr = 4 waves; wave owns 32 q rows as TWO 16-row groups sharing every
// K/V LDS fragment read.  S^T = MFMA16(K,Q); softmax lane-local; P goes
// through a per-wave private LDS buffer (4 ds_write_b64 + 2 ds_read_b128).
// Grid 1024: bh = wg&63 (XCD affinity), qt = 15-(wg>>6) longest-first.
// 2-slot double buffer, counted vmcnt(4); 40 KB LDS -> 4 blocks/CU.
__global__ __launch_bounds__(256, 3) void attn128(const __half* __restrict__ Q,
                                                  const __half* __restrict__ K,
                                                  const __half* __restrict__ Vt,
                                                  __half* __restrict__ O) {
  const int wg = blockIdx.x;
  const int bh = wg & 63;
  const int qt = 15 - (wg >> 6);
  const int b = bh >> 4, h = bh & 15;
  const int tid = threadIdx.x;
  const int w = tid >> 6, lane = tid & 63;
  const int lr = lane & 15, lq = lane >> 4;

  __shared__ alignas(16) __half Ks[2][4096];
  __shared__ alignas(16) __half Vs[2][4096];
  __shared__ alignas(16) unsigned Pl[4][512];  // per-wave P: [16 q][32 u32]

  const __half* Kb = K + (size_t)bh * 131072;
  const __half* Vb = Vt + (size_t)bh * 131072;

  const int srow0 = tid >> 3;
  const int srow1 = srow0 + 32;
  const int scol = ((tid & 7) ^ (srow0 & 7)) * 8;

#define STAGE(t, buf)                                                          \
  do {                                                                         \
    gload_lds16(Kb + (size_t)((t)*64 + srow0) * 64 + scol, Ks[buf] + tid * 8); \
    gload_lds16(Kb + (size_t)((t)*64 + srow1) * 64 + scol,                     \
                Ks[buf] + 2048 + tid * 8);                                     \
    gload_lds16(Vb + (size_t)srow0 * 2048 + (t)*64 + scol, Vs[buf] + tid * 8); \
    gload_lds16(Vb + (size_t)srow1 * 2048 + (t)*64 + scol,                     \
                Vs[buf] + 2048 + tid * 8);                                     \
  } while (0)

  const int q0 = qt * 128;
  const int ktend = 2 * qt + 2;
  const int rmin = q0 + w * 32;
  const int myqa = rmin + lr;
  const int myqb = rmin + 16 + lr;

  const __half* Qpa = Q + ((size_t)bh * 2048 + rmin) * 64;
  half8 qf0a = *(const half8*)(Qpa + lr * 64 + lq * 8);
  half8 qf1a = *(const half8*)(Qpa + lr * 64 + 32 + lq * 8);
  half8 qf0b = *(const half8*)(Qpa + (16 + lr) * 64 + lq * 8);
  half8 qf1b = *(const half8*)(Qpa + (16 + lr) * 64 + 32 + lq * 8);

  f32x4 oacca[4] = {}, oaccb[4] = {};
  float ma = -INFINITY, la = 0.f, mb = -INFINITY, lb = 0.f;

  STAGE(0, 0);
  asm volatile("" ::: "memory");

  char* Pc = (char*)Pl[w];

  // softmax + pack + LDS round-trip for one 16-q group (inlined twice).
  // l is a per-lane PARTIAL (sum over this lane's 16 keys); reduced at end.
  auto smgrp = [&](f32x4* sacc, float& m, float& l, int myq, int k0,
                   bool needmask, f32x4* oacc, half8& pa0, half8& pa1) {
    if (needmask) {
#pragma unroll
      for (int nt = 0; nt < 4; ++nt)
#pragma unroll
        for (int r = 0; r < 4; ++r) {
          int key = k0 + nt * 16 + lq * 4 + r;
          if (key > myq) sacc[nt][r] = -INFINITY;
        }
    }
    float rm = fmaxf(sacc[0][0], sacc[0][1]);
    rm = fmaxf(fmaxf(rm, sacc[0][2]), sacc[0][3]);
    rm = fmaxf(fmaxf(rm, sacc[1][0]), sacc[1][1]);
    rm = fmaxf(fmaxf(rm, sacc[1][2]), sacc[1][3]);
    rm = fmaxf(fmaxf(rm, sacc[2][0]), sacc[2][1]);
    rm = fmaxf(fmaxf(rm, sacc[2][2]), sacc[2][3]);
    rm = fmaxf(fmaxf(rm, sacc[3][0]), sacc[3][1]);
    rm = fmaxf(fmaxf(rm, sacc[3][2]), sacc[3][3]);
    rm = fmaxf(rm, __shfl_xor(rm, 16));
    rm = fmaxf(rm, __shfl_xor(rm, 32));
    if (__any(rm > m + 8.f)) {  // defer-max (T13)
      float mn = fmaxf(m, rm);
      float al = __builtin_amdgcn_exp2f(m - mn);
      m = mn;
      l *= al;
      float al4[4];
#pragma unroll
      for (int r = 0; r < 4; ++r) al4[r] = __shfl(al, lq * 4 + r);
#pragma unroll
      for (int dt = 0; dt < 4; ++dt)
#pragma unroll
        for (int r = 0; r < 4; ++r) oacc[dt][r] *= al4[r];
    }
    float ps = 0.f;
#pragma unroll
    for (int nt = 0; nt < 4; ++nt) {
      float p0 = __builtin_amdgcn_exp2f(sacc[nt][0] - m);
      float p1 = __builtin_amdgcn_exp2f(sacc[nt][1] - m);
      float p2 = __builtin_amdgcn_exp2f(sacc[nt][2] - m);
      float p3 = __builtin_amdgcn_exp2f(sacc[nt][3] - m);
      sacc[nt][0] = p0; sacc[nt][1] = p1;
      sacc[nt][2] = p2; sacc[nt][3] = p3;
      ps += (p0 + p1) + (p2 + p3);
    }
    l += ps;  // deferred: cross-lane reduce once in epilogue
    // pack pairs and write P[q=lr][key=nt*16+lq*4+{0..3}] as one b64
#pragma unroll
    for (int nt = 0; nt < 4; ++nt) {
      __half2 pha = __floats2half2_rn(sacc[nt][0], sacc[nt][1]);
      __half2 phb = __floats2half2_rn(sacc[nt][2], sacc[nt][3]);
      u32x2 pw;
      pw[0] = *(unsigned*)&pha;
      pw[1] = *(unsigned*)&phb;
      *(u32x2*)(Pc + ((lr * 128 + nt * 32 + lq * 8) ^ ((lr & 7) << 4))) = pw;
    }
    pa0 = *(const half8*)(Pc + ((lr * 128 + lq * 16) ^ ((lr & 7) << 4)));
    pa1 = *(const half8*)(Pc + ((lr * 128 + 64 + lq * 16) ^ ((lr & 7) << 4)));
  };

  for (int kt = 0; kt < ktend; ++kt) {
    const int cur = kt & 1;
    const int k0 = kt * 64;
    if (kt + 1 < ktend) {
      STAGE(kt + 1, cur ^ 1);
      asm volatile("s_waitcnt vmcnt(4)" ::: "memory");
    } else {
      asm volatile("s_waitcnt vmcnt(0)" ::: "memory");
    }
    __builtin_amdgcn_s_barrier();
    asm volatile("" ::: "memory");

    const char* Kc = (const char*)Ks[cur];
    const char* Vc = (const char*)Vs[cur];
    if (k0 <= rmin + 31) {
      f32x4 sa[4] = {}, sb[4] = {};
      __builtin_amdgcn_s_setprio(1);
#pragma unroll
      for (int nt = 0; nt < 4; ++nt) {
        int row = nt * 16 + lr;
        half8 kb0 = *(const half8*)(Kc + ((row * 128 + lq * 16) ^ ((row & 7) << 4)));
        half8 kb1 = *(const half8*)(Kc + ((row * 128 + 64 + lq * 16) ^ ((row & 7) << 4)));
        sa[nt] = MFMA16(kb0, qf0a, sa[nt]);
        sa[nt] = MFMA16(kb1, qf1a, sa[nt]);
        sb[nt] = MFMA16(kb0, qf0b, sb[nt]);
        sb[nt] = MFMA16(kb1, qf1b, sb[nt]);
      }
      __builtin_amdgcn_s_setprio(0);

      half8 paa0, paa1, pab0, pab1;
      smgrp(sa, ma, la, myqa, k0, k0 + 63 > rmin, oacca, paa0, paa1);
      smgrp(sb, mb, lb, myqb, k0, k0 + 63 > rmin + 16, oaccb, pab0, pab1);

      __builtin_amdgcn_s_setprio(1);
#pragma unroll
      for (int dt = 0; dt < 4; ++dt) {
        int row = dt * 16 + lr;
        half8 vb0 = *(const half8*)(Vc + ((row * 128 + lq * 16) ^ ((row & 7) << 4)));
        half8 vb1 = *(const half8*)(Vc + ((row * 128 + 64 + lq * 16) ^ ((row & 7) << 4)));
        oacca[dt] = MFMA16(paa0, vb0, oacca[dt]);
        oacca[dt] = MFMA16(paa1, vb1, oacca[dt]);
        oaccb[dt] = MFMA16(pab0, vb0, oaccb[dt]);
        oaccb[dt] = MFMA16(pab1, vb1, oaccb[dt]);
      }
      __builtin_amdgcn_s_setprio(0);
    }
    asm volatile("s_waitcnt lgkmcnt(0)" ::: "memory");
    __builtin_amdgcn_s_barrier();
    asm volatile("" ::: "memory");
  }

  // epilogue: reduce deferred l across the 4 lane-groups, broadcast, write
  auto epi = [&](f32x4* oacc, float lpart, int grow) {
    float lt = lpart;
    lt += __shfl_xor(lt, 16);
    lt += __shfl_xor(lt, 32);
    float linv = 1.0f / lt;
    float inv4[4];
#pragma unroll
    for (int r = 0; r < 4; ++r) inv4[r] = __shfl(linv, lq * 4 + r);
    __half* Op = O + ((size_t)b * 2048 + rmin + grow) * 1024 + h * 64;
#pragma unroll
    for (int dt = 0; dt < 4; ++dt)
#pragma unroll
      for (int r = 0; r < 4; ++r)
        Op[(size_t)(lq * 4 + r) * 1024 + dt * 16 + lr] =
            __float2half(oacc[dt][r] * inv4[r]);
  };
  epi(oacca, la, 0);
  epi(oaccb, lb, 16);
#undef STAGE
}

// ---------------- launch ---------------------------------------------------
extern "C" void kernel_launch(void* const* d_in, const int* in_sizes, int n_in,
                              void* d_out, int out_size, void* d_ws,
                              size_t ws_size, hipStream_t stream) {
  const float* x = (const float*)d_in[0];
  const float* Wq = (const float*)d_in[1];
  const float* bq = (const float*)d_in[2];
  const float* Wk = (const float*)d_in[3];
  const float* bk = (const float*)d_in[4];
  const float* Wv = (const float*)d_in[5];
  const float* bv = (const float*)d_in[6];
  const float* Wp = (const float*)d_in[7];
  const float* bp = (const float*)d_in[8];

  // workspace layout (bytes)
  char* ws = (char*)d_ws;
  const size_t XB = 0;                       // 16777216
  const size_t WQKV = XB + 16777216;         // 6291456
  const size_t WPB = WQKV + 6291456;         // 2097152
  const size_t QKV = WPB + 2097152;          // 50331648 (v slot unused)
  const size_t VT = QKV + 50331648;          // 16777216
  const size_t OB = VT + 16777216;           // 16777216  (~109 MiB)

  __half* xb = (__half*)(ws + XB);
  __half* wqkv = (__half*)(ws + WQKV);
  __half* wpb = (__half*)(ws + WPB);
  __half* qkv = (__half*)(ws + QKV);
  __half* vt = (__half*)(ws + VT);
  __half* ob = (__half*)(ws + OB);

  // fused cast: x + Wq + Wk + Wv + Wp (1572864 half8 units)
  cast_all<<<6144, 256, 0, stream>>>(x, Wq, Wk, Wv, Wp, xb, wqkv, wpb);

  // QKV: M=8192, N=3072, 256x192 tile, 4-phase counted-vmcnt schedule
  gemmQKV<<<dim3(16, 32), 512, 0, stream>>>(xb, wqkv, bq, bk, bv, qkv, vt);
  // attention: 1024 blocks, longest-first, dual-Q, LDS-P redistribute
  attn128<<<dim3(1024), 256, 0, stream>>>(qkv, qkv + 8388608, vt, ob);
  // proj: M=8192, N=1024, f32 out + bias (T2-swizzled LDS)
  gemm128p<<<dim3(8, 64), 256, 0, stream>>>(ob, wpb, bp, (float*)d_out);
}

// Round 21
// 166.020 us; speedup vs baseline: 1.1165x; 1.0116x over previous
//
#include <hip/hip_runtime.h>
#include <hip/hip_fp16.h>

// Problem constants: B=4, N=2048, D=1024, H=16, DH=64.  M = B*N = 8192.

typedef _Float16 half8 __attribute__((ext_vector_type(8)));
typedef _Float16 half4 __attribute__((ext_vector_type(4)));
typedef float f32x4 __attribute__((ext_vector_type(4)));
typedef unsigned int u32x2 __attribute__((ext_vector_type(2)));

#define DEV __device__ __forceinline__
#define MFMA16(a, b, c) __builtin_amdgcn_mfma_f32_16x16x32_f16(a, b, c, 0, 0, 0)

DEV void gload_lds16(const void* g, void* l) {
  __builtin_amdgcn_global_load_lds(
      (const __attribute__((address_space(1))) void*)g,
      (__attribute__((address_space(3))) void*)l, 16, 0, 0);
}

// ---------------- fused cast f32 -> f16 (x + 4 weight matrices) ------------
__global__ __launch_bounds__(256) void cast_all(
    const float* __restrict__ x, const float* __restrict__ Wq,
    const float* __restrict__ Wk, const float* __restrict__ Wv,
    const float* __restrict__ Wp, __half* __restrict__ xb,
    __half* __restrict__ wqkv, __half* __restrict__ wpb) {
  int i = blockIdx.x * 256 + threadIdx.x;
  const float* s;
  __half* d;
  int j;
  if (i < 1048576) {
    s = x; d = xb; j = i;
  } else {
    int k = i - 1048576;
    int sel = k >> 17;
    j = k & 131071;
    s = (sel == 0) ? Wq : (sel == 1) ? Wk : (sel == 2) ? Wv : Wp;
    d = (sel == 3) ? wpb : (wqkv + sel * 1048576);
  }
  const float4* sp = (const float4*)s + (size_t)j * 2;
  float4 a = sp[0], b = sp[1];
  half8 h;
  h[0] = (_Float16)a.x; h[1] = (_Float16)a.y; h[2] = (_Float16)a.z; h[3] = (_Float16)a.w;
  h[4] = (_Float16)b.x; h[5] = (_Float16)b.y; h[6] = (_Float16)b.z; h[7] = (_Float16)b.w;
  *((half8*)d + j) = h;
}

// ---------------- 128x192 QKV GEMM, 2 blocks/CU co-resident ----------------
// A: [8192][1024] f16.  Bm: [3072][1024] f16.  K=1024, BK=64, 16 K-tiles.
// Tile 128x192, 4 waves (2M x 2N), per-wave 64x96 = acc[4][6].
// LDS = 2 dbuf x (A 128x64 + B 192x64) x 2B = 80 KB -> EXACTLY 2 blocks/CU
// (r15/r16/r17 all ran 1 block/CU and all plateaued at ~73.5us: no second
// block to hide barrier drains -- the m114 overlap mechanism).  Grid 16x64
// = 1024 blocks = 4 balanced CU rounds.  T2 swizzle; counted vmcnt(10)
// (stage t+1's 10 loads, certify tile t, never drain to 0 mid-loop).
__global__ __launch_bounds__(256, 2) void gemmQKV(
    const __half* __restrict__ A, const __half* __restrict__ Bm,
    const float* __restrict__ b0, const float* __restrict__ b1,
    const float* __restrict__ b2, __half* __restrict__ oh,
    __half* __restrict__ vtp) {
  const int n0 = blockIdx.x * 192;
  const int m0 = blockIdx.y * 128;
  const int tid = threadIdx.x;
  const int w = tid >> 6, lane = tid & 63;
  const int lr = lane & 15, lq = lane >> 4;
  const int wr = w >> 1, wc = w & 1;  // 2M x 2N

  __shared__ alignas(16) __half As[2][8192];   // 128 x 64 halves, swizzled
  __shared__ alignas(16) __half Bs[2][12288];  // 192 x 64 halves, swizzled

  f32x4 acc[4][6] = {};

  // staging: 256 thr x 16B = 32 rows per load group; srow&7 invariant
  const int srow = tid >> 3;
  const int scol = ((tid & 7) ^ (srow & 7)) * 8;
  const __half* Agp = A + ((size_t)m0 + srow) * 1024 + scol;
  const __half* Bgp = Bm + ((size_t)n0 + srow) * 1024 + scol;

#define STG(kt, buf)                                                           \
  do {                                                                         \
    const __half* ag = Agp + (kt)*64;                                          \
    const __half* bg = Bgp + (kt)*64;                                          \
    gload_lds16(ag, As[buf] + tid * 8);                                        \
    gload_lds16(ag + 32768, As[buf] + 2048 + tid * 8);                         \
    gload_lds16(ag + 65536, As[buf] + 4096 + tid * 8);                         \
    gload_lds16(ag + 98304, As[buf] + 6144 + tid * 8);                         \
    gload_lds16(bg, Bs[buf] + tid * 8);                                        \
    gload_lds16(bg + 32768, Bs[buf] + 2048 + tid * 8);                         \
    gload_lds16(bg + 65536, Bs[buf] + 4096 + tid * 8);                         \
    gload_lds16(bg + 98304, Bs[buf] + 6144 + tid * 8);                         \
    gload_lds16(bg + 131072, Bs[buf] + 8192 + tid * 8);                        \
    gload_lds16(bg + 163840, Bs[buf] + 10240 + tid * 8);                       \
  } while (0)

  STG(0, 0);
  asm volatile("" ::: "memory");

  for (int t = 0; t < 16; ++t) {
    const int s = t & 1;
    if (t < 15) {
      STG(t + 1, s ^ 1);
      asm volatile("s_waitcnt vmcnt(10)" ::: "memory");
    } else {
      asm volatile("s_waitcnt vmcnt(0)" ::: "memory");
    }
    __builtin_amdgcn_s_barrier();
    asm volatile("" ::: "memory");

    const char* Ac = (const char*)As[s];
    const char* Bc = (const char*)Bs[s];
    __builtin_amdgcn_s_setprio(1);
#pragma unroll
    for (int ks = 0; ks < 2; ++ks) {
      half8 af[4], bf[6];
#pragma unroll
      for (int mi = 0; mi < 4; ++mi) {
        int row = wr * 64 + mi * 16 + lr;
        af[mi] = *(const half8*)(Ac + ((row * 128 + ks * 64 + lq * 16) ^ ((row & 7) << 4)));
      }
#pragma unroll
      for (int ni = 0; ni < 6; ++ni) {
        int row = wc * 96 + ni * 16 + lr;
        bf[ni] = *(const half8*)(Bc + ((row * 128 + ks * 64 + lq * 16) ^ ((row & 7) << 4)));
      }
#pragma unroll
      for (int mi = 0; mi < 4; ++mi)
#pragma unroll
        for (int ni = 0; ni < 6; ++ni)
          acc[mi][ni] = MFMA16(af[mi], bf[ni], acc[mi][ni]);
    }
    __builtin_amdgcn_s_setprio(0);

    asm volatile("s_waitcnt lgkmcnt(0)" ::: "memory");
    __builtin_amdgcn_s_barrier();
    asm volatile("" ::: "memory");
  }

  // ---- QKV scatter epilogue ----
#pragma unroll
  for (int ni = 0; ni < 6; ++ni) {
    int col = n0 + wc * 96 + ni * 16 + lr;
    int t = col >> 10, e = col & 1023;
    const float* bb = (t == 0) ? b0 : ((t == 1) ? b1 : b2);
    float bias = bb[e];
    int hh = e >> 6, dh = e & 63;
    if (t == 2) {
      // V: transposed write vt[(b*16+hh)][dh][n], 4 consecutive n = 8B
#pragma unroll
      for (int mi = 0; mi < 4; ++mi) {
        int row = m0 + wr * 64 + mi * 16 + lq * 4;
        int b_ = row >> 11, n = row & 2047;
        half4 h;
#pragma unroll
        for (int r = 0; r < 4; ++r) h[r] = (_Float16)(acc[mi][ni][r] + bias);
        *(half4*)(vtp + (size_t)(b_ * 16 + hh) * 131072 + (size_t)dh * 2048 + n) = h;
      }
    } else {
      float scale = (t == 0) ? 11.541560327111707f : 1.0f;
      __half* base = oh + (size_t)t * 8388608 + dh;
#pragma unroll
      for (int mi = 0; mi < 4; ++mi)
#pragma unroll
        for (int r = 0; r < 4; ++r) {
          int row = m0 + wr * 64 + mi * 16 + lq * 4 + r;
          int b_ = row >> 11, n = row & 2047;
          float v = (acc[mi][ni][r] + bias) * scale;
          base[(((size_t)(b_ * 16 + hh) * 2048 + n) * 64)] = __float2half(v);
        }
    }
  }
#undef STG
}

// ---------------- 128x128 GEMM (proj), T2-swizzled LDS ---------------------
__global__ __launch_bounds__(256) void gemm128p(
    const __half* __restrict__ A, const __half* __restrict__ Bm,
    const float* __restrict__ b0, float* __restrict__ of) {
  const int m0 = blockIdx.y * 128;
  const int n0 = blockIdx.x * 128;
  const int tid = threadIdx.x;
  const int w = tid >> 6, lane = tid & 63;
  const int lr = lane & 15, lq = lane >> 4;
  const int wr = w >> 1, wc = w & 1;

  __shared__ alignas(16) __half As[128 * 64];
  __shared__ alignas(16) __half Bs[128 * 64];

  f32x4 acc[4][4] = {};

  const int arow = lane >> 3;
  const int acol = ((lane & 7) ^ arow) * 8;
  const __half* Agp = A + ((size_t)m0 + w * 32 + arow) * 1024 + acol;
  const __half* Bgp = Bm + ((size_t)n0 + w * 32 + arow) * 1024 + acol;

  for (int kt = 0; kt < 16; ++kt) {
#pragma unroll
    for (int j = 0; j < 4; ++j) {
      gload_lds16(Agp + j * 8192 + kt * 64, As + (w * 4 + j) * 512);
      gload_lds16(Bgp + j * 8192 + kt * 64, Bs + (w * 4 + j) * 512);
    }
    __syncthreads();
#pragma unroll
    for (int s = 0; s < 2; ++s) {
      half8 af[4], bf[4];
#pragma unroll
      for (int i = 0; i < 4; ++i) {
        int rowA = wr * 64 + i * 16 + lr;
        int rowB = wc * 64 + i * 16 + lr;
        af[i] = *(const half8*)((const char*)As +
                                ((rowA * 128 + s * 64 + lq * 16) ^ ((rowA & 7) << 4)));
        bf[i] = *(const half8*)((const char*)Bs +
                                ((rowB * 128 + s * 64 + lq * 16) ^ ((rowB & 7) << 4)));
      }
#pragma unroll
      for (int mi = 0; mi < 4; ++mi)
#pragma unroll
        for (int ni = 0; ni < 4; ++ni)
          acc[mi][ni] = MFMA16(af[mi], bf[ni], acc[mi][ni]);
    }
    __syncthreads();
  }

#pragma unroll
  for (int ni = 0; ni < 4; ++ni) {
    int col = n0 + wc * 64 + ni * 16 + lr;
    float bias = b0[col];
#pragma unroll
    for (int mi = 0; mi < 4; ++mi)
#pragma unroll
      for (int r = 0; r < 4; ++r) {
        int row = m0 + wr * 64 + mi * 16 + lq * 4 + r;
        of[(size_t)row * 1024 + col] = acc[mi][ni][r] + bias;
      }
  }
}

// ---------------- causal flash attention (r15, verified: ~62us) ------------
__global__ __launch_bounds__(256, 3) void attn128(const __half* __restrict__ Q,
                                                  const __half* __restrict__ K,
                                                  const __half* __restrict__ Vt,
                                                  __half* __restrict__ O) {
  const int wg = blockIdx.x;
  const int bh = wg & 63;
  const int qt = 15 - (wg >> 6);
  const int b = bh >> 4, h = bh & 15;
  const int tid = threadIdx.x;
  const int w = tid >> 6, lane = tid & 63;
  const int lr = lane & 15, lq = lane >> 4;

  __shared__ alignas(16) __half Ks[2][4096];
  __shared__ alignas(16) __half Vs[2][4096];
  __shared__ alignas(16) unsigned Pl[4][512];  // per-wave P: [16 q][32 u32]

  const __half* Kb = K + (size_t)bh * 131072;
  const __half* Vb = Vt + (size_t)bh * 131072;

  const int srow0 = tid >> 3;
  const int srow1 = srow0 + 32;
  const int scol = ((tid & 7) ^ (srow0 & 7)) * 8;

#define STAGE(t, buf)                                                          \
  do {                                                                         \
    gload_lds16(Kb + (size_t)((t)*64 + srow0) * 64 + scol, Ks[buf] + tid * 8); \
    gload_lds16(Kb + (size_t)((t)*64 + srow1) * 64 + scol,                     \
                Ks[buf] + 2048 + tid * 8);                                     \
    gload_lds16(Vb + (size_t)srow0 * 2048 + (t)*64 + scol, Vs[buf] + tid * 8); \
    gload_lds16(Vb + (size_t)srow1 * 2048 + (t)*64 + scol,                     \
                Vs[buf] + 2048 + tid * 8);                                     \
  } while (0)

  const int q0 = qt * 128;
  const int ktend = 2 * qt + 2;
  const int rmin = q0 + w * 32;
  const int myqa = rmin + lr;
  const int myqb = rmin + 16 + lr;

  const __half* Qpa = Q + ((size_t)bh * 2048 + rmin) * 64;
  half8 qf0a = *(const half8*)(Qpa + lr * 64 + lq * 8);
  half8 qf1a = *(const half8*)(Qpa + lr * 64 + 32 + lq * 8);
  half8 qf0b = *(const half8*)(Qpa + (16 + lr) * 64 + lq * 8);
  half8 qf1b = *(const half8*)(Qpa + (16 + lr) * 64 + 32 + lq * 8);

  f32x4 oacca[4] = {}, oaccb[4] = {};
  float ma = -INFINITY, la = 0.f, mb = -INFINITY, lb = 0.f;

  STAGE(0, 0);
  asm volatile("" ::: "memory");

  char* Pc = (char*)Pl[w];

  auto smgrp = [&](f32x4* sacc, float& m, float& l, int myq, int k0,
                   bool needmask, f32x4* oacc, half8& pa0, half8& pa1) {
    if (needmask) {
#pragma unroll
      for (int nt = 0; nt < 4; ++nt)
#pragma unroll
        for (int r = 0; r < 4; ++r) {
          int key = k0 + nt * 16 + lq * 4 + r;
          if (key > myq) sacc[nt][r] = -INFINITY;
        }
    }
    float rm = fmaxf(sacc[0][0], sacc[0][1]);
    rm = fmaxf(fmaxf(rm, sacc[0][2]), sacc[0][3]);
    rm = fmaxf(fmaxf(rm, sacc[1][0]), sacc[1][1]);
    rm = fmaxf(fmaxf(rm, sacc[1][2]), sacc[1][3]);
    rm = fmaxf(fmaxf(rm, sacc[2][0]), sacc[2][1]);
    rm = fmaxf(fmaxf(rm, sacc[2][2]), sacc[2][3]);
    rm = fmaxf(fmaxf(rm, sacc[3][0]), sacc[3][1]);
    rm = fmaxf(fmaxf(rm, sacc[3][2]), sacc[3][3]);
    rm = fmaxf(rm, __shfl_xor(rm, 16));
    rm = fmaxf(rm, __shfl_xor(rm, 32));
    if (__any(rm > m + 8.f)) {  // defer-max (T13)
      float mn = fmaxf(m, rm);
      float al = __builtin_amdgcn_exp2f(m - mn);
      m = mn;
      l *= al;
      float al4[4];
#pragma unroll
      for (int r = 0; r < 4; ++r) al4[r] = __shfl(al, lq * 4 + r);
#pragma unroll
      for (int dt = 0; dt < 4; ++dt)
#pragma unroll
        for (int r = 0; r < 4; ++r) oacc[dt][r] *= al4[r];
    }
    float ps = 0.f;
#pragma unroll
    for (int nt = 0; nt < 4; ++nt) {
      float p0 = __builtin_amdgcn_exp2f(sacc[nt][0] - m);
      float p1 = __builtin_amdgcn_exp2f(sacc[nt][1] - m);
      float p2 = __builtin_amdgcn_exp2f(sacc[nt][2] - m);
      float p3 = __builtin_amdgcn_exp2f(sacc[nt][3] - m);
      sacc[nt][0] = p0; sacc[nt][1] = p1;
      sacc[nt][2] = p2; sacc[nt][3] = p3;
      ps += (p0 + p1) + (p2 + p3);
    }
    l += ps;  // deferred: cross-lane reduce once in epilogue
#pragma unroll
    for (int nt = 0; nt < 4; ++nt) {
      __half2 pha = __floats2half2_rn(sacc[nt][0], sacc[nt][1]);
      __half2 phb = __floats2half2_rn(sacc[nt][2], sacc[nt][3]);
      u32x2 pw;
      pw[0] = *(unsigned*)&pha;
      pw[1] = *(unsigned*)&phb;
      *(u32x2*)(Pc + ((lr * 128 + nt * 32 + lq * 8) ^ ((lr & 7) << 4))) = pw;
    }
    pa0 = *(const half8*)(Pc + ((lr * 128 + lq * 16) ^ ((lr & 7) << 4)));
    pa1 = *(const half8*)(Pc + ((lr * 128 + 64 + lq * 16) ^ ((lr & 7) << 4)));
  };

  for (int kt = 0; kt < ktend; ++kt) {
    const int cur = kt & 1;
    const int k0 = kt * 64;
    if (kt + 1 < ktend) {
      STAGE(kt + 1, cur ^ 1);
      asm volatile("s_waitcnt vmcnt(4)" ::: "memory");
    } else {
      asm volatile("s_waitcnt vmcnt(0)" ::: "memory");
    }
    __builtin_amdgcn_s_barrier();
    asm volatile("" ::: "memory");

    const char* Kc = (const char*)Ks[cur];
    const char* Vc = (const char*)Vs[cur];
    if (k0 <= rmin + 31) {
      f32x4 sa[4] = {}, sb[4] = {};
      __builtin_amdgcn_s_setprio(1);
#pragma unroll
      for (int nt = 0; nt < 4; ++nt) {
        int row = nt * 16 + lr;
        half8 kb0 = *(const half8*)(Kc + ((row * 128 + lq * 16) ^ ((row & 7) << 4)));
        half8 kb1 = *(const half8*)(Kc + ((row * 128 + 64 + lq * 16) ^ ((row & 7) << 4)));
        sa[nt] = MFMA16(kb0, qf0a, sa[nt]);
        sa[nt] = MFMA16(kb1, qf1a, sa[nt]);
        sb[nt] = MFMA16(kb0, qf0b, sb[nt]);
        sb[nt] = MFMA16(kb1, qf1b, sb[nt]);
      }
      __builtin_amdgcn_s_setprio(0);

      half8 paa0, paa1, pab0, pab1;
      smgrp(sa, ma, la, myqa, k0, k0 + 63 > rmin, oacca, paa0, paa1);
      smgrp(sb, mb, lb, myqb, k0, k0 + 63 > rmin + 16, oaccb, pab0, pab1);

      __builtin_amdgcn_s_setprio(1);
#pragma unroll
      for (int dt = 0; dt < 4; ++dt) {
        int row = dt * 16 + lr;
        half8 vb0 = *(const half8*)(Vc + ((row * 128 + lq * 16) ^ ((row & 7) << 4)));
        half8 vb1 = *(const half8*)(Vc + ((row * 128 + 64 + lq * 16) ^ ((row & 7) << 4)));
        oacca[dt] = MFMA16(paa0, vb0, oacca[dt]);
        oacca[dt] = MFMA16(paa1, vb1, oacca[dt]);
        oaccb[dt] = MFMA16(pab0, vb0, oaccb[dt]);
        oaccb[dt] = MFMA16(pab1, vb1, oaccb[dt]);
      }
      __builtin_amdgcn_s_setprio(0);
    }
    asm volatile("s_waitcnt lgkmcnt(0)" ::: "memory");
    __builtin_amdgcn_s_barrier();
    asm volatile("" ::: "memory");
  }

  auto epi = [&](f32x4* oacc, float lpart, int grow) {
    float lt = lpart;
    lt += __shfl_xor(lt, 16);
    lt += __shfl_xor(lt, 32);
    float linv = 1.0f / lt;
    float inv4[4];
#pragma unroll
    for (int r = 0; r < 4; ++r) inv4[r] = __shfl(linv, lq * 4 + r);
    __half* Op = O + ((size_t)b * 2048 + rmin + grow) * 1024 + h * 64;
#pragma unroll
    for (int dt = 0; dt < 4; ++dt)
#pragma unroll
      for (int r = 0; r < 4; ++r)
        Op[(size_t)(lq * 4 + r) * 1024 + dt * 16 + lr] =
            __float2half(oacc[dt][r] * inv4[r]);
  };
  epi(oacca, la, 0);
  epi(oaccb, lb, 16);
#undef STAGE
}

// ---------------- launch ---------------------------------------------------
extern "C" void kernel_launch(void* const* d_in, const int* in_sizes, int n_in,
                              void* d_out, int out_size, void* d_ws,
                              size_t ws_size, hipStream_t stream) {
  const float* x = (const float*)d_in[0];
  const float* Wq = (const float*)d_in[1];
  const float* bq = (const float*)d_in[2];
  const float* Wk = (const float*)d_in[3];
  const float* bk = (const float*)d_in[4];
  const float* Wv = (const float*)d_in[5];
  const float* bv = (const float*)d_in[6];
  const float* Wp = (const float*)d_in[7];
  const float* bp = (const float*)d_in[8];

  // workspace layout (bytes)
  char* ws = (char*)d_ws;
  const size_t XB = 0;                       // 16777216
  const size_t WQKV = XB + 16777216;         // 6291456
  const size_t WPB = WQKV + 6291456;         // 2097152
  const size_t QKV = WPB + 2097152;          // 50331648 (v slot unused)
  const size_t VT = QKV + 50331648;          // 16777216
  const size_t OB = VT + 16777216;           // 16777216  (~109 MiB)

  __half* xb = (__half*)(ws + XB);
  __half* wqkv = (__half*)(ws + WQKV);
  __half* wpb = (__half*)(ws + WPB);
  __half* qkv = (__half*)(ws + QKV);
  __half* vt = (__half*)(ws + VT);
  __half* ob = (__half*)(ws + OB);

  // fused cast: x + Wq + Wk + Wv + Wp (1572864 half8 units)
  cast_all<<<6144, 256, 0, stream>>>(x, Wq, Wk, Wv, Wp, xb, wqkv, wpb);

  // QKV: M=8192, N=3072, 128x192 tile, 2 blocks/CU co-resident
  gemmQKV<<<dim3(16, 64), 256, 0, stream>>>(xb, wqkv, bq, bk, bv, qkv, vt);
  // attention: 1024 blocks, longest-first, dual-Q, LDS-P redistribute
  attn128<<<dim3(1024), 256, 0, stream>>>(qkv, qkv + 8388608, vt, ob);
  // proj: M=8192, N=1024, f32 out + bias (T2-swizzled LDS)
  gemm128p<<<dim3(8, 64), 256, 0, stream>>>(ob, wpb, bp, (float*)d_out);
}